// Round 8
// baseline (2285.410 us; speedup 1.0000x reference)
//
#include <hip/hip_runtime.h>
#include <math.h>

// Problem dims (reference: N, Fin, E, H1, H2 = 128, 512, 128, 256, 128)
constexpr int Nn  = 128;   // nodes
constexpr int FIN = 512;   // input feature dim
constexpr int EE  = 128;   // embed dim E
constexpr int H1n = 256;   // hidden 1 (= 2E)
constexpr int H2n = 128;   // hidden 2

// ---------------------------------------------------------------------------
// Precompute 1: G0 = feature_origin @ W_e (pre-bias, pre-relu)   [128][128]
//               feat = relu(G0 + b_e)   (feat lives in d_out)
// ---------------------------------------------------------------------------
__global__ void precomp1(const float* __restrict__ fo, const float* __restrict__ We,
                         const float* __restrict__ be,
                         float* __restrict__ G0, float* __restrict__ feat)
{
    const int n = blockIdx.x;
    const int j = threadIdx.x;        // 0..127
    float acc = 0.f;
    for (int k = 0; k < FIN; ++k)
        acc += fo[n * FIN + k] * We[k * EE + j];
    G0[n * EE + j] = acc;
    feat[n * EE + j] = fmaxf(acc + be[j], 0.f);
}

// ---------------------------------------------------------------------------
// Precompute 2: BcurG[n] = relu(G0[n]+be) @ W1_bot (rows 128..255) [128][256]
// (seqk copies this into its LDS-resident Bcur cache once)
// ---------------------------------------------------------------------------
__global__ void precomp2(const float* __restrict__ G0, const float* __restrict__ be,
                         const float* __restrict__ W1,
                         float* __restrict__ BcurG)
{
    __shared__ float f[EE];
    const int n = blockIdx.x;
    const int j = threadIdx.x;        // 0..255
    if (j < EE) f[j] = fmaxf(G0[n * EE + j] + be[j], 0.f);
    __syncthreads();
    float acc = 0.f;
    for (int k = 0; k < EE; ++k)
        acc += f[k] * W1[(EE + k) * H1n + j];
    BcurG[n * H1n + j] = acc;
}

// ---------------------------------------------------------------------------
// Sequential policy kernel: ONE block, 512 threads.
//   W1 (256KB) in registers: t<256 -> W1_top col t; t>=256 -> W1_bot col t-256.
//   W2 (128KB) in registers: thread (kq=t>>7, j=t&127) holds W2[kq*64..+64)[j].
//   Bcur [128][256] lives in LDS. All scalar control replicated per-thread.
// 5 barriers/step. G0 candidate rows prefetched during P1 (T14 split).
// ---------------------------------------------------------------------------
__global__ __launch_bounds__(512, 2) void seqk(
    const float* __restrict__ adj,  const float* __restrict__ W1,
    const float* __restrict__ b1,   const float* __restrict__ W2,
    const float* __restrict__ b2,   const float* __restrict__ wlk,
    const float* __restrict__ blkb, const float* __restrict__ wact,
    const float* __restrict__ bact, const float* __restrict__ be,
    const float* __restrict__ G0,   const float* __restrict__ BcurG,
    float* __restrict__ feat)
{
    __shared__ float bc[Nn * H1n];     // 128 KB Bcur cache
    __shared__ float h1[4][H1n];       // 4 KB
    __shared__ float pa[4][4][H2n];    // 8 KB partials
    __shared__ float u[H1n];           // x @ W1_top
    __shared__ float ubi[H1n];         // x @ W1_bot (valid when needb)
    __shared__ float xsh[EE], gi[EE], gsum[EE];
    __shared__ float gc[3 * EE];       // prefetched G0 candidate rows
    __shared__ float sbe[EE], sb1[H1n], sb2[H2n], swlk[H2n], swact[2 * H2n];
    __shared__ float rb_lk[8], rb_a0[8], rb_a1[8];
    __shared__ unsigned long long mlds[2];

    const int tid = threadIdx.x;

    // ---- prologue: persistent weights ----
    float w1reg[128];                  // one W1 column per thread
    {
        const int col = tid & 255;
        const int rbase = (tid < 256) ? 0 : EE;
        #pragma unroll
        for (int k = 0; k < 128; ++k)
            w1reg[k] = W1[(rbase + k) * H1n + col];
    }
    float w2reg[64];                   // 64-k slice of W2 column j
    {
        const int kq = tid >> 7, j = tid & 127;
        #pragma unroll
        for (int kk = 0; kk < 64; ++kk)
            w2reg[kk] = W2[(kq * 64 + kk) * H2n + j];
    }
    #pragma unroll
    for (int q = 0; q < 16; ++q) {     // Bcur global -> LDS (one-time)
        const int idx = (q * 512 + tid) * 4;
        *reinterpret_cast<float4*>(&bc[idx]) =
            *reinterpret_cast<const float4*>(&BcurG[idx]);
    }
    if (tid < EE)  sbe[tid] = be[tid];
    if (tid < H1n) sb1[tid] = b1[tid];
    if (tid < H2n) { sb2[tid] = b2[tid]; swlk[tid] = wlk[tid]; }
    if (tid < 2 * H2n) swact[tid] = wact[tid];
    const float r_blk = blkb[0], r_ba0 = bact[0], r_ba1 = bact[1];
    unsigned long long um0 = 0ULL, um1 = 0ULL;     // replicated updated-mask
    __syncthreads();

    for (int i = 0; i < Nn; ++i) {
        // ---- node init ----
        if (tid < EE) { xsh[tid] = feat[i * EE + tid]; gsum[tid] = 0.f; }
        if (tid < 32)
            *reinterpret_cast<float4*>(&gi[tid * 4]) =
                *reinterpret_cast<const float4*>(&G0[i * EE + tid * 4]);
        if (tid < Nn) {
            const bool c = adj[i * Nn + tid] != 0.f;
            const unsigned long long m = __ballot(c);
            if ((tid & 63) == 0) mlds[tid >> 6] = m;
        }
        __syncthreads();
        unsigned long long cm0 = mlds[0], cm1 = mlds[1];   // replicated cand mask
        unsigned long long sel0 = 0ULL, sel1 = 0ULL;
        float cnt = 0.f;
        int xdirty = 0;

        for (int s = 0; s < 4; ++s) {
            // ---- replicated candidate extraction (ascending index) ----
            int cl[4]; int ncand = 0;
            {
                unsigned long long m0 = cm0, m1 = cm1;
                #pragma unroll
                for (int t = 0; t < 4; ++t) {
                    int v = -1;
                    if (m0) { v = __builtin_ctzll(m0); m0 &= m0 - 1; }
                    else if (m1) { v = 64 + __builtin_ctzll(m1); m1 &= m1 - 1; }
                    cl[t] = v;
                    if (v >= 0) ++ncand;
                }
            }
            const int needb = (cl[0] == i) | (cl[1] == i) | (cl[2] == i) | (cl[3] == i);

            // ---- P1: u/ubi matvec; threads 0-95 prefetch G0 cand rows ----
            const int pr = tid >> 5, pf = tid & 31;
            const bool havegc = (tid < 96) && (pr < ncand);
            float4 gtmp;
            if (havegc) {
                const int v = (pr == 0) ? cl[0] : (pr == 1) ? cl[1] : cl[2];
                gtmp = *reinterpret_cast<const float4*>(&G0[v * EE + pf * 4]);
            }
            if (tid < 256 || needb) {
                float a0 = 0.f, a1 = 0.f, a2 = 0.f, a3 = 0.f;
                #pragma unroll
                for (int q = 0; q < 32; ++q) {
                    const float4 xv = *reinterpret_cast<const float4*>(&xsh[q * 4]);
                    a0 += xv.x * w1reg[q * 4 + 0];
                    a1 += xv.y * w1reg[q * 4 + 1];
                    a2 += xv.z * w1reg[q * 4 + 2];
                    a3 += xv.w * w1reg[q * 4 + 3];
                }
                const float sres = (a0 + a1) + (a2 + a3);
                if (tid < 256) u[tid] = sres; else ubi[tid - 256] = sres;
            }
            if (havegc)
                *reinterpret_cast<float4*>(&gc[pr * EE + pf * 4]) = gtmp;
            __syncthreads();   // B1

            // ---- P2a: h1 rows = cand + sentinel (extra rows zeroed) ----
            {
                const int half = tid >> 8, k = tid & 255;
                #pragma unroll
                for (int hh = 0; hh < 2; ++hh) {
                    const int r = hh * 2 + half;
                    const int v = (half == 0) ? (hh == 0 ? cl[0] : cl[2])
                                              : (hh == 0 ? cl[1] : cl[3]);
                    float hv = 0.f;
                    if (r <= ncand) {                       // r==ncand: sentinel
                        float Bv = 0.f;
                        if (r < ncand && v > 0)             // v==0 quirk -> 0
                            Bv = (v == i && needb) ? ubi[k] : bc[v * H1n + k];
                        hv = fmaxf(u[k] + Bv + sb1[k], 0.f);
                    }
                    h1[r][k] = hv;
                }
            }
            __syncthreads();   // B2

            // ---- P2b: partials with register-held W2 (h1 reads broadcast) ----
            {
                const int kq = tid >> 7, j = tid & 127;
                const int kb = kq * 64;
                float ac0 = 0.f, ac1 = 0.f, ac2 = 0.f, ac3 = 0.f;
                #pragma unroll
                for (int kk = 0; kk < 64; kk += 4) {
                    const float4 h0 = *reinterpret_cast<const float4*>(&h1[0][kb + kk]);
                    const float4 hv1 = *reinterpret_cast<const float4*>(&h1[1][kb + kk]);
                    const float4 hv2 = *reinterpret_cast<const float4*>(&h1[2][kb + kk]);
                    const float4 hv3 = *reinterpret_cast<const float4*>(&h1[3][kb + kk]);
                    const float w0 = w2reg[kk], w1_ = w2reg[kk + 1];
                    const float w2_ = w2reg[kk + 2], w3 = w2reg[kk + 3];
                    ac0 += h0.x * w0 + h0.y * w1_ + h0.z * w2_ + h0.w * w3;
                    ac1 += hv1.x * w0 + hv1.y * w1_ + hv1.z * w2_ + hv1.w * w3;
                    ac2 += hv2.x * w0 + hv2.y * w1_ + hv2.z * w2_ + hv2.w * w3;
                    ac3 += hv3.x * w0 + hv3.y * w1_ + hv3.z * w2_ + hv3.w * w3;
                }
                pa[kq][0][j] = ac0; pa[kq][1][j] = ac1;
                pa[kq][2][j] = ac2; pa[kq][3][j] = ac3;
            }
            __syncthreads();   // B3

            // ---- D: h2 + fused lk / act0 / act1 reductions ----
            {
                const int r = tid >> 7, j = tid & 127;
                const float v = pa[0][r][j] + pa[1][r][j] + pa[2][r][j] + pa[3][r][j]
                                + sb2[j];
                const float hval = fmaxf(v, 0.f);
                float plk = hval * swlk[j];
                float p0  = hval * swact[2 * j];
                float p1  = hval * swact[2 * j + 1];
                #pragma unroll
                for (int off = 32; off; off >>= 1) {
                    plk += __shfl_down(plk, off);
                    p0  += __shfl_down(p0, off);
                    p1  += __shfl_down(p1, off);
                }
                if ((tid & 63) == 0) {
                    const int w = tid >> 6;
                    rb_lk[w] = plk; rb_a0[w] = p0; rb_a1[w] = p1;
                }
            }
            __syncthreads();   // B4

            // ---- E': replicated decision (argmax first-max, action) ----
            float lkv[4];
            #pragma unroll
            for (int r = 0; r < 4; ++r)
                lkv[r] = rb_lk[2 * r] + rb_lk[2 * r + 1] + r_blk;
            float bv = -INFINITY; int ut = -1, rsel = -1;
            #pragma unroll
            for (int r = 0; r < 4; ++r)
                if (r < ncand && lkv[r] > bv) { bv = lkv[r]; ut = cl[r]; rsel = r; }
            const float slk = (ncand == 0) ? lkv[0] : (ncand == 1) ? lkv[1]
                            : (ncand == 2) ? lkv[2] : lkv[3];
            const bool brk = (ut < 0) || (slk > bv);
            if (brk) break;    // uniform; reference: done for remaining steps
            const float a0v = rb_a0[2 * rsel] + rb_a0[2 * rsel + 1] + r_ba0;
            const float a1v = rb_a1[2 * rsel] + rb_a1[2 * rsel + 1] + r_ba1;
            const int at = (a1v > a0v) ? 1 : 0;
            const int utc = ut;
            const bool selOld =
                ((utc < 64 ? (sel0 >> utc) : (sel1 >> (utc - 64))) & 1ULL) != 0ULL;
            const float denom = cnt + (float)at + 1.0f;   // pre-update cnt
            // replicated state update
            if (at && !selOld) {
                cnt += 1.f;
                if (utc < 64) sel0 |= 1ULL << utc; else sel1 |= 1ULL << (utc - 64);
            }
            if (utc < 64) cm0 &= ~(1ULL << utc); else cm1 &= ~(1ULL << (utc - 64));
            if (i < 64) um0 |= 1ULL << i; else um1 |= 1ULL << (i - 64);
            if (utc < 64) um0 |= 1ULL << utc; else um1 |= 1ULL << (utc - 64);
            xdirty = (utc != i) ? 1 : 0;

            // ---- F: wide update (0-127) || Bcur[utc] recompute (256-511) ----
            if (tid < EE) {
                const float g_ut = gc[rsel * EE + tid];
                const float futc = fmaxf(g_ut + sbe[tid], 0.f);   // F0[utc]
                const float z = (gsum[tid] + (float)at * g_ut + gi[tid]) / denom
                                + sbe[tid];
                float nx = fmaxf(z, 0.f);
                if (utc == i) nx = futc;                 // .at[utc] write wins
                xsh[tid] = nx;
                if (utc != i) feat[i * EE + tid] = nx;
                feat[utc * EE + tid] = futc;
                if (at && !selOld) gsum[tid] += g_ut;
            } else if (tid >= 256) {
                // bc[utc] = relu(G0[utc]+be) @ W1_bot  (== precomp2, same order)
                const int c = tid - 256;
                float acc = 0.f;
                #pragma unroll
                for (int k = 0; k < 128; ++k) {
                    const float f = fmaxf(gc[rsel * EE + k] + sbe[k], 0.f);
                    acc = fmaf(f, w1reg[k], acc);
                }
                bc[utc * H1n + c] = acc;
            }
            __syncthreads();   // B5
        } // steps

        // node end: feature[i] left as embed(hv) -> refresh bc[i] via regs
        if (xdirty && tid >= 256) {
            const int c = tid - 256;
            float a0 = 0.f, a1 = 0.f, a2 = 0.f, a3 = 0.f;
            #pragma unroll
            for (int q = 0; q < 32; ++q) {
                const float4 xv = *reinterpret_cast<const float4*>(&xsh[q * 4]);
                a0 += xv.x * w1reg[q * 4 + 0];
                a1 += xv.y * w1reg[q * 4 + 1];
                a2 += xv.z * w1reg[q * 4 + 2];
                a3 += xv.w * w1reg[q * 4 + 3];
            }
            bc[i * H1n + c] = (a0 + a1) + (a2 + a3);
        }
        __syncthreads();       // node end (protects xsh/bc before next node)
    } // nodes

    // out = where(updated, feat, 0) — in place on d_out (um replicated)
    for (int idx = tid; idx < Nn * EE; idx += 512) {
        const int n = idx >> 7;   // EE = 128
        const bool upd = ((n < 64 ? (um0 >> n) : (um1 >> (n - 64))) & 1ULL) != 0ULL;
        const float v = feat[idx];
        feat[idx] = upd ? v : 0.f;
    }
}

// ---------------------------------------------------------------------------
extern "C" void kernel_launch(void* const* d_in, const int* in_sizes, int n_in,
                              void* d_out, int out_size, void* d_ws, size_t ws_size,
                              hipStream_t stream)
{
    (void)in_sizes; (void)n_in; (void)out_size; (void)ws_size;
    const float* adj  = (const float*)d_in[0];
    const float* fo   = (const float*)d_in[1];
    // d_in[2] = labels (unused by the forward pass)
    const float* We   = (const float*)d_in[3];
    const float* be   = (const float*)d_in[4];
    const float* W1   = (const float*)d_in[5];
    const float* b1   = (const float*)d_in[6];
    const float* W2   = (const float*)d_in[7];
    const float* b2   = (const float*)d_in[8];
    const float* wlk  = (const float*)d_in[9];
    const float* blkb = (const float*)d_in[10];
    const float* wact = (const float*)d_in[11];
    const float* bact = (const float*)d_in[12];

    float* ws    = (float*)d_ws;
    float* G0    = ws;                // 128*128 floats (64 KB)
    float* BcurG = ws + 16384;        // 128*256 floats (128 KB)
    float* feat  = (float*)d_out;     // evolving feature table lives in d_out

    hipLaunchKernelGGL(precomp1, dim3(Nn), dim3(EE), 0, stream, fo, We, be, G0, feat);
    hipLaunchKernelGGL(precomp2, dim3(Nn), dim3(H1n), 0, stream, G0, be, W1, BcurG);
    hipLaunchKernelGGL(seqk, dim3(1), dim3(512), 0, stream,
                       adj, W1, b1, W2, b2, wlk, blkb, wact, bact, be,
                       G0, BcurG, feat);
}

// Round 9
// 2051.673 us; speedup vs baseline: 1.1139x; 1.1139x over previous
//
#include <hip/hip_runtime.h>
#include <math.h>

// Problem dims (reference: N, Fin, E, H1, H2 = 128, 512, 128, 256, 128)
constexpr int Nn  = 128;   // nodes
constexpr int FIN = 512;   // input feature dim
constexpr int EE  = 128;   // embed dim E
constexpr int H1n = 256;   // hidden 1 (= 2E)
constexpr int H2n = 128;   // hidden 2

// ---------------------------------------------------------------------------
// Precompute 1: G0 = feature_origin @ W_e (pre-bias, pre-relu)   [128][128]
//               feat = relu(G0 + b_e)   (feat lives in d_out)
// ---------------------------------------------------------------------------
__global__ void precomp1(const float* __restrict__ fo, const float* __restrict__ We,
                         const float* __restrict__ be,
                         float* __restrict__ G0, float* __restrict__ feat)
{
    const int n = blockIdx.x;
    const int j = threadIdx.x;        // 0..127
    float acc = 0.f;
    for (int k = 0; k < FIN; ++k)
        acc += fo[n * FIN + k] * We[k * EE + j];
    G0[n * EE + j] = acc;
    feat[n * EE + j] = fmaxf(acc + be[j], 0.f);
}

// ---------------------------------------------------------------------------
// Precompute 2: BcurG[n] = relu(G0[n]+be) @ W1_bot (rows 128..255) [128][256]
// seqk copies this into its LDS bc cache; BcurG stays PRISTINE (reset source).
// ---------------------------------------------------------------------------
__global__ void precomp2(const float* __restrict__ G0, const float* __restrict__ be,
                         const float* __restrict__ W1,
                         float* __restrict__ BcurG)
{
    __shared__ float f[EE];
    const int n = blockIdx.x;
    const int j = threadIdx.x;        // 0..255
    if (j < EE) f[j] = fmaxf(G0[n * EE + j] + be[j], 0.f);
    __syncthreads();
    float acc = 0.f;
    for (int k = 0; k < EE; ++k)
        acc += f[k] * W1[(EE + k) * H1n + j];
    BcurG[n * H1n + j] = acc;
}

// ---------------------------------------------------------------------------
// P2b body, templated on live row count (nrows = ncand+1, wave-uniform).
// Rows >= NR are never read downstream (E' uses lkv[r<ncand] + sentinel only).
// ---------------------------------------------------------------------------
template<int NR>
__device__ __forceinline__ void p2b_rows(const float h1[4][H1n],
                                         const float* __restrict__ w2,
                                         float pa[4][4][H2n],
                                         const int kq, const int j)
{
    const int kb = kq * 64;
    float ac[NR];
    #pragma unroll
    for (int r = 0; r < NR; ++r) ac[r] = 0.f;
    #pragma unroll
    for (int kk = 0; kk < 64; kk += 4) {
        const float w0 = w2[kk], w1_ = w2[kk + 1], w2_ = w2[kk + 2], w3 = w2[kk + 3];
        #pragma unroll
        for (int r = 0; r < NR; ++r) {
            const float4 h = *reinterpret_cast<const float4*>(&h1[r][kb + kk]);
            ac[r] += h.x * w0 + h.y * w1_ + h.z * w2_ + h.w * w3;
        }
    }
    #pragma unroll
    for (int r = 0; r < NR; ++r) pa[kq][r][j] = ac[r];
}

// ---------------------------------------------------------------------------
// Sequential policy kernel: ONE block, 512 threads.
//   W1 (256KB) in registers: t<256 -> W1_top col t; t>=256 -> W1_bot col t-256.
//   W2 (128KB) in registers: thread (kq=t>>7, j=t&127) holds W2[kq*64..+64)[j].
//   Bcur [128][256] in LDS; reset rows restored by COPY from pristine BcurG.
//   All scalar control replicated per-thread. 5 barriers/step.
// __launch_bounds__(512,1): single block => occupancy fixed at 2 waves/SIMD
// anyway; the relaxed bound lets the 192 weight floats live in ARCH VGPRs
// (avoids v_accvgpr_read on every FMA operand).
// ---------------------------------------------------------------------------
__global__ __launch_bounds__(512, 1) void seqk(
    const float* __restrict__ adj,  const float* __restrict__ W1,
    const float* __restrict__ b1,   const float* __restrict__ W2,
    const float* __restrict__ b2,   const float* __restrict__ wlk,
    const float* __restrict__ blkb, const float* __restrict__ wact,
    const float* __restrict__ bact, const float* __restrict__ be,
    const float* __restrict__ G0,   const float* __restrict__ BcurG,
    float* __restrict__ feat)
{
    __shared__ float bc[Nn * H1n];     // 128 KB Bcur cache
    __shared__ float h1[4][H1n];       // 4 KB
    __shared__ float pa[4][4][H2n];    // 8 KB partials
    __shared__ float u[H1n];           // x @ W1_top
    __shared__ float ubi[H1n];         // x @ W1_bot (valid when needb)
    __shared__ float xsh[EE], gi[EE], gsum[EE];
    __shared__ float gc[3 * EE];       // prefetched G0 candidate rows
    __shared__ float sbe[EE], sb1[H1n], sb2[H2n], swlk[H2n], swact[2 * H2n];
    __shared__ float rb_lk[8], rb_a0[8], rb_a1[8];
    __shared__ unsigned long long mlds[2];

    const int tid = threadIdx.x;

    // ---- prologue: persistent weights ----
    float w1reg[128];                  // one W1 column per thread
    {
        const int col = tid & 255;
        const int rbase = (tid < 256) ? 0 : EE;
        #pragma unroll
        for (int k = 0; k < 128; ++k)
            w1reg[k] = W1[(rbase + k) * H1n + col];
    }
    float w2reg[64];                   // 64-k slice of W2 column j
    {
        const int kq = tid >> 7, j = tid & 127;
        #pragma unroll
        for (int kk = 0; kk < 64; ++kk)
            w2reg[kk] = W2[(kq * 64 + kk) * H2n + j];
    }
    #pragma unroll
    for (int q = 0; q < 16; ++q) {     // Bcur global -> LDS (one-time)
        const int idx = (q * 512 + tid) * 4;
        *reinterpret_cast<float4*>(&bc[idx]) =
            *reinterpret_cast<const float4*>(&BcurG[idx]);
    }
    if (tid < EE)  sbe[tid] = be[tid];
    if (tid < H1n) sb1[tid] = b1[tid];
    if (tid < H2n) { sb2[tid] = b2[tid]; swlk[tid] = wlk[tid]; }
    if (tid < 2 * H2n) swact[tid] = wact[tid];
    const float r_blk = blkb[0], r_ba0 = bact[0], r_ba1 = bact[1];
    unsigned long long um0 = 0ULL, um1 = 0ULL;     // replicated updated-mask
    __syncthreads();

    for (int i = 0; i < Nn; ++i) {
        // ---- node init ----
        if (tid < EE) { xsh[tid] = feat[i * EE + tid]; gsum[tid] = 0.f; }
        if (tid < 32)
            *reinterpret_cast<float4*>(&gi[tid * 4]) =
                *reinterpret_cast<const float4*>(&G0[i * EE + tid * 4]);
        if (tid < Nn) {
            const bool c = adj[i * Nn + tid] != 0.f;
            const unsigned long long m = __ballot(c);
            if ((tid & 63) == 0) mlds[tid >> 6] = m;
        }
        __syncthreads();
        unsigned long long cm0 = mlds[0], cm1 = mlds[1];   // replicated cand mask
        unsigned long long sel0 = 0ULL, sel1 = 0ULL;
        float cnt = 0.f;
        int xdirty = 0;

        for (int s = 0; s < 4; ++s) {
            // ---- replicated candidate extraction (ascending index) ----
            int cl[4]; int ncand = 0;
            {
                unsigned long long m0 = cm0, m1 = cm1;
                #pragma unroll
                for (int t = 0; t < 4; ++t) {
                    int v = -1;
                    if (m0) { v = __builtin_ctzll(m0); m0 &= m0 - 1; }
                    else if (m1) { v = 64 + __builtin_ctzll(m1); m1 &= m1 - 1; }
                    cl[t] = v;
                    if (v >= 0) ++ncand;
                }
            }
            const int needb = (cl[0] == i) | (cl[1] == i) | (cl[2] == i) | (cl[3] == i);

            // ---- P1: u/ubi matvec; threads 0-95 prefetch G0 cand rows ----
            const int pr = tid >> 5, pf = tid & 31;
            const bool havegc = (tid < 96) && (pr < ncand);
            float4 gtmp;
            if (havegc) {
                const int v = (pr == 0) ? cl[0] : (pr == 1) ? cl[1] : cl[2];
                gtmp = *reinterpret_cast<const float4*>(&G0[v * EE + pf * 4]);
            }
            if (tid < 256 || needb) {
                float a0 = 0.f, a1 = 0.f, a2 = 0.f, a3 = 0.f;
                #pragma unroll
                for (int q = 0; q < 32; ++q) {
                    const float4 xv = *reinterpret_cast<const float4*>(&xsh[q * 4]);
                    a0 += xv.x * w1reg[q * 4 + 0];
                    a1 += xv.y * w1reg[q * 4 + 1];
                    a2 += xv.z * w1reg[q * 4 + 2];
                    a3 += xv.w * w1reg[q * 4 + 3];
                }
                const float sres = (a0 + a1) + (a2 + a3);
                if (tid < 256) u[tid] = sres; else ubi[tid - 256] = sres;
            }
            if (havegc)
                *reinterpret_cast<float4*>(&gc[pr * EE + pf * 4]) = gtmp;
            __syncthreads();   // B1

            // ---- P2a: h1 rows = cand + sentinel (rows > ncand untouched) ----
            {
                const int half = tid >> 8, k = tid & 255;
                #pragma unroll
                for (int hh = 0; hh < 2; ++hh) {
                    const int r = hh * 2 + half;
                    const int v = (half == 0) ? (hh == 0 ? cl[0] : cl[2])
                                              : (hh == 0 ? cl[1] : cl[3]);
                    if (r <= ncand) {                       // r==ncand: sentinel
                        float Bv = 0.f;
                        if (r < ncand && v > 0)             // v==0 quirk -> 0
                            Bv = (v == i && needb) ? ubi[k] : bc[v * H1n + k];
                        h1[r][k] = fmaxf(u[k] + Bv + sb1[k], 0.f);
                    }
                }
            }
            __syncthreads();   // B2

            // ---- P2b: partials, only live rows (nrows = ncand+1 uniform) ----
            {
                const int kq = tid >> 7, j = tid & 127;
                switch (ncand) {
                    case 3:  p2b_rows<4>(h1, w2reg, pa, kq, j); break;
                    case 2:  p2b_rows<3>(h1, w2reg, pa, kq, j); break;
                    case 1:  p2b_rows<2>(h1, w2reg, pa, kq, j); break;
                    default: p2b_rows<1>(h1, w2reg, pa, kq, j); break;
                }
            }
            __syncthreads();   // B3

            // ---- D: h2 + fused lk / act0 / act1 reductions ----
            // (rows r > ncand read stale pa -> garbage, but E' never uses them)
            {
                const int r = tid >> 7, j = tid & 127;
                const float v = pa[0][r][j] + pa[1][r][j] + pa[2][r][j] + pa[3][r][j]
                                + sb2[j];
                const float hval = fmaxf(v, 0.f);
                float plk = hval * swlk[j];
                float p0  = hval * swact[2 * j];
                float p1  = hval * swact[2 * j + 1];
                #pragma unroll
                for (int off = 32; off; off >>= 1) {
                    plk += __shfl_down(plk, off);
                    p0  += __shfl_down(p0, off);
                    p1  += __shfl_down(p1, off);
                }
                if ((tid & 63) == 0) {
                    const int w = tid >> 6;
                    rb_lk[w] = plk; rb_a0[w] = p0; rb_a1[w] = p1;
                }
            }
            __syncthreads();   // B4

            // ---- E': replicated decision (argmax first-max, action) ----
            float lkv[4];
            #pragma unroll
            for (int r = 0; r < 4; ++r)
                lkv[r] = rb_lk[2 * r] + rb_lk[2 * r + 1] + r_blk;
            float bv = -INFINITY; int ut = -1, rsel = -1;
            #pragma unroll
            for (int r = 0; r < 4; ++r)
                if (r < ncand && lkv[r] > bv) { bv = lkv[r]; ut = cl[r]; rsel = r; }
            const float slk = (ncand == 0) ? lkv[0] : (ncand == 1) ? lkv[1]
                            : (ncand == 2) ? lkv[2] : lkv[3];
            const bool brk = (ut < 0) || (slk > bv);
            if (brk) break;    // uniform; reference: done for remaining steps
            const float a0v = rb_a0[2 * rsel] + rb_a0[2 * rsel + 1] + r_ba0;
            const float a1v = rb_a1[2 * rsel] + rb_a1[2 * rsel + 1] + r_ba1;
            const int at = (a1v > a0v) ? 1 : 0;
            const int utc = ut;
            const bool selOld =
                ((utc < 64 ? (sel0 >> utc) : (sel1 >> (utc - 64))) & 1ULL) != 0ULL;
            const float denom = cnt + (float)at + 1.0f;   // pre-update cnt
            // replicated state update
            if (at && !selOld) {
                cnt += 1.f;
                if (utc < 64) sel0 |= 1ULL << utc; else sel1 |= 1ULL << (utc - 64);
            }
            if (utc < 64) cm0 &= ~(1ULL << utc); else cm1 &= ~(1ULL << (utc - 64));
            if (i < 64) um0 |= 1ULL << i; else um1 |= 1ULL << (i - 64);
            if (utc < 64) um0 |= 1ULL << utc; else um1 |= 1ULL << (utc - 64);
            xdirty = (utc != i) ? 1 : 0;

            // ---- F: wide update (0-127) || bc[utc] reset by COPY (256-511) ----
            if (tid < EE) {
                const float g_ut = gc[rsel * EE + tid];
                const float futc = fmaxf(g_ut + sbe[tid], 0.f);   // F0[utc]
                const float z = (gsum[tid] + (float)at * g_ut + gi[tid]) / denom
                                + sbe[tid];
                float nx = fmaxf(z, 0.f);
                if (utc == i) nx = futc;                 // .at[utc] write wins
                xsh[tid] = nx;
                if (utc != i) feat[i * EE + tid] = nx;
                feat[utc * EE + tid] = futc;
                if (at && !selOld) gsum[tid] += g_ut;
            } else if (tid >= 256) {
                // bc[utc] reset = pristine B0 row (BcurG untouched since init)
                const int c = tid - 256;
                bc[utc * H1n + c] = BcurG[utc * H1n + c];
            }
            __syncthreads();   // B5
        } // steps

        // node end: feature[i] left as embed(hv) -> refresh bc[i] via regs
        if (xdirty && tid >= 256) {
            const int c = tid - 256;
            float a0 = 0.f, a1 = 0.f, a2 = 0.f, a3 = 0.f;
            #pragma unroll
            for (int q = 0; q < 32; ++q) {
                const float4 xv = *reinterpret_cast<const float4*>(&xsh[q * 4]);
                a0 += xv.x * w1reg[q * 4 + 0];
                a1 += xv.y * w1reg[q * 4 + 1];
                a2 += xv.z * w1reg[q * 4 + 2];
                a3 += xv.w * w1reg[q * 4 + 3];
            }
            bc[i * H1n + c] = (a0 + a1) + (a2 + a3);
        }
        __syncthreads();       // node end (protects xsh/bc before next node)
    } // nodes

    // out = where(updated, feat, 0) — in place on d_out (um replicated)
    for (int idx = tid; idx < Nn * EE; idx += 512) {
        const int n = idx >> 7;   // EE = 128
        const bool upd = ((n < 64 ? (um0 >> n) : (um1 >> (n - 64))) & 1ULL) != 0ULL;
        const float v = feat[idx];
        feat[idx] = upd ? v : 0.f;
    }
}

// ---------------------------------------------------------------------------
extern "C" void kernel_launch(void* const* d_in, const int* in_sizes, int n_in,
                              void* d_out, int out_size, void* d_ws, size_t ws_size,
                              hipStream_t stream)
{
    (void)in_sizes; (void)n_in; (void)out_size; (void)ws_size;
    const float* adj  = (const float*)d_in[0];
    const float* fo   = (const float*)d_in[1];
    // d_in[2] = labels (unused by the forward pass)
    const float* We   = (const float*)d_in[3];
    const float* be   = (const float*)d_in[4];
    const float* W1   = (const float*)d_in[5];
    const float* b1   = (const float*)d_in[6];
    const float* W2   = (const float*)d_in[7];
    const float* b2   = (const float*)d_in[8];
    const float* wlk  = (const float*)d_in[9];
    const float* blkb = (const float*)d_in[10];
    const float* wact = (const float*)d_in[11];
    const float* bact = (const float*)d_in[12];

    float* ws    = (float*)d_ws;
    float* G0    = ws;                // 128*128 floats (64 KB)
    float* BcurG = ws + 16384;        // 128*256 floats (128 KB) — stays pristine
    float* feat  = (float*)d_out;     // evolving feature table lives in d_out

    hipLaunchKernelGGL(precomp1, dim3(Nn), dim3(EE), 0, stream, fo, We, be, G0, feat);
    hipLaunchKernelGGL(precomp2, dim3(Nn), dim3(H1n), 0, stream, G0, be, W1, BcurG);
    hipLaunchKernelGGL(seqk, dim3(1), dim3(512), 0, stream,
                       adj, W1, b1, W2, b2, wlk, blkb, wact, bact, be,
                       G0, BcurG, feat);
}